// Round 1
// baseline (31.297 us; speedup 1.0000x reference)
//
#include <hip/hip_runtime.h>
#include <math.h>

#define D_IN 512
#define NQ 4
#define QD 6

// ---------------------------------------------------------------------------
// Kernel 1: pre-net GEMV + tanh -> half-angles.
// One wave (64 lanes) per sample: lane l loads x[row*512 + l*4 ..] as float4
// (perfectly coalesced, 1KB per load instruction per wave), accumulates 4
// partial dots, butterfly-reduces, lanes 0..3 write theta/2 per qubit.
// ---------------------------------------------------------------------------
__global__ __launch_bounds__(256) void dqn_gemv(
    const float* __restrict__ x,
    const float* __restrict__ pre_w,
    const float* __restrict__ pre_b,
    float* __restrict__ half_ang,
    int nsamp)
{
    const int lane = threadIdx.x & 63;
    const int samp = blockIdx.x * 4 + (threadIdx.x >> 6);
    if (samp >= nsamp) return;

    const float4* xr = reinterpret_cast<const float4*>(x) + (size_t)samp * (D_IN / 4);
    const float4* wr = reinterpret_cast<const float4*>(pre_w);

    float a0 = 0.f, a1 = 0.f, a2 = 0.f, a3 = 0.f;
#pragma unroll
    for (int h = 0; h < 2; ++h) {
        const int o = lane + h * 64;
        float4 xv = xr[o];
        float4 w0 = wr[0 * (D_IN / 4) + o];   // pre_w rows: L1-resident (8 KB)
        float4 w1 = wr[1 * (D_IN / 4) + o];
        float4 w2 = wr[2 * (D_IN / 4) + o];
        float4 w3 = wr[3 * (D_IN / 4) + o];
        a0 += xv.x * w0.x + xv.y * w0.y + xv.z * w0.z + xv.w * w0.w;
        a1 += xv.x * w1.x + xv.y * w1.y + xv.z * w1.z + xv.w * w1.w;
        a2 += xv.x * w2.x + xv.y * w2.y + xv.z * w2.z + xv.w * w2.w;
        a3 += xv.x * w3.x + xv.y * w3.y + xv.z * w3.z + xv.w * w3.w;
    }
    // 64-lane butterfly reduction (wave = 64 on CDNA!)
#pragma unroll
    for (int m = 32; m >= 1; m >>= 1) {
        a0 += __shfl_xor(a0, m, 64);
        a1 += __shfl_xor(a1, m, 64);
        a2 += __shfl_xor(a2, m, 64);
        a3 += __shfl_xor(a3, m, 64);
    }
    if (lane < 4) {
        float t = (lane == 0) ? a0 : (lane == 1) ? a1 : (lane == 2) ? a2 : a3;
        t += pre_b[lane];
        // tanh(t) = 1 - 2/(e^{2t}+1); overflow of __expf -> inf -> tanh -> 1 (correct)
        float e = __expf(2.0f * t);
        float th = 1.0f - 2.0f / (e + 1.0f);
        // store HALF angle: theta/2 = tanh * pi/4 (RY uses theta/2)
        half_ang[(size_t)samp * 4 + lane] = th * 0.78539816339744831f;
    }
}

// ---------------------------------------------------------------------------
// Kernel 2: 4-qubit statevector sim + post-net. One thread per sample.
// State index: idx = b0*8 + b1*4 + b2*2 + b3 (wire w -> bit (8>>w)).
// H then RY(angle) on all wires == product state:
//   A_w(0) = (c-s)/sqrt2, A_w(1) = (c+s)/sqrt2.
// All loops fully unrolled -> st[16] stays in registers (rule #20).
// ---------------------------------------------------------------------------
__global__ __launch_bounds__(256) void dqn_sim(
    const float* __restrict__ half_ang,
    const float* __restrict__ q_params,
    const float* __restrict__ post_w,
    const float* __restrict__ post_b,
    float* __restrict__ out,
    int nsamp)
{
    const int b = blockIdx.x * 256 + threadIdx.x;
    if (b >= nsamp) return;

    // per-layer RY weights (uniform across threads; cached loads)
    float qc[QD][NQ], qs[QD][NQ];
#pragma unroll
    for (int k = 0; k < QD; ++k)
#pragma unroll
        for (int w = 0; w < NQ; ++w)
            __sincosf(q_params[k * NQ + w] * 0.5f, &qs[k][w], &qc[k][w]);

    float4 ha = reinterpret_cast<const float4*>(half_ang)[b];
    float s0, c0, s1, c1, s2, c2, s3, c3;
    __sincosf(ha.x, &s0, &c0);
    __sincosf(ha.y, &s1, &c1);
    __sincosf(ha.z, &s2, &c2);
    __sincosf(ha.w, &s3, &c3);

    const float r2 = 0.70710678118654752f;
    float A0[2] = {(c0 - s0) * r2, (c0 + s0) * r2};
    float A1[2] = {(c1 - s1) * r2, (c1 + s1) * r2};
    float A2[2] = {(c2 - s2) * r2, (c2 + s2) * r2};
    float A3[2] = {(c3 - s3) * r2, (c3 + s3) * r2};

    float u[4], v[4], st[16];
#pragma unroll
    for (int i = 0; i < 4; ++i) { u[i] = A0[i >> 1] * A1[i & 1]; v[i] = A2[i >> 1] * A3[i & 1]; }
#pragma unroll
    for (int i = 0; i < 16; ++i) st[i] = u[i >> 2] * v[i & 3];

#pragma unroll
    for (int k = 0; k < QD; ++k) {
        // CNOT(0,1): b0=1 -> swap b1: (8,12)(9,13)(10,14)(11,15)
#pragma unroll
        for (int j = 0; j < 4; ++j) { float t = st[8 + j]; st[8 + j] = st[12 + j]; st[12 + j] = t; }
        // CNOT(2,3): b2=1 -> swap b3: (2,3)(6,7)(10,11)(14,15)
#pragma unroll
        for (int j = 0; j < 4; ++j) { float t = st[4 * j + 2]; st[4 * j + 2] = st[4 * j + 3]; st[4 * j + 3] = t; }
        // CNOT(1,2): b1=1 -> swap b2: (4,6)(5,7)(12,14)(13,15)
#pragma unroll
        for (int j = 0; j < 2; ++j)
#pragma unroll
            for (int d = 0; d < 2; ++d) {
                const int i0 = j * 8 + 4 + d;
                float t = st[i0]; st[i0] = st[i0 + 2]; st[i0 + 2] = t;
            }
        // RY on each wire
#pragma unroll
        for (int w = 0; w < NQ; ++w) {
            const int m = 8 >> w;
            const float c = qc[k][w], s = qs[k][w];
#pragma unroll
            for (int i = 0; i < 16; ++i) {
                if ((i & m) == 0) {
                    float x0 = st[i], x1 = st[i | m];
                    st[i]     = c * x0 - s * x1;
                    st[i | m] = s * x0 + c * x1;
                }
            }
        }
    }

    // PauliZ expectations
    float e0 = 0.f, e1 = 0.f, e2 = 0.f, e3 = 0.f;
#pragma unroll
    for (int i = 0; i < 16; ++i) {
        float p = st[i] * st[i];
        e0 += (i & 8) ? -p : p;
        e1 += (i & 4) ? -p : p;
        e2 += (i & 2) ? -p : p;
        e3 += (i & 1) ? -p : p;
    }

    // post-net: out[b][c] = post_b[c] + sum_w e_w * post_w[c][w]
    float* orow = out + (size_t)b * 10;
#pragma unroll
    for (int c = 0; c < 10; ++c) {
        orow[c] = post_b[c] + e0 * post_w[c * 4 + 0] + e1 * post_w[c * 4 + 1]
                + e2 * post_w[c * 4 + 2] + e3 * post_w[c * 4 + 3];
    }
}

extern "C" void kernel_launch(void* const* d_in, const int* in_sizes, int n_in,
                              void* d_out, int out_size, void* d_ws, size_t ws_size,
                              hipStream_t stream)
{
    const float* x      = (const float*)d_in[0];
    const float* pre_w  = (const float*)d_in[1];
    const float* pre_b  = (const float*)d_in[2];
    const float* q_par  = (const float*)d_in[3];
    const float* post_w = (const float*)d_in[4];
    const float* post_b = (const float*)d_in[5];
    float* out = (float*)d_out;

    const int nsamp = in_sizes[0] / D_IN;        // 65536
    float* half_ang = (float*)d_ws;              // nsamp*4 floats = 1 MB scratch

    dim3 blk(256);
    dim3 g1((nsamp + 3) / 4);                    // 4 waves/block, 1 sample/wave
    dqn_gemv<<<g1, blk, 0, stream>>>(x, pre_w, pre_b, half_ang, nsamp);

    dim3 g2((nsamp + 255) / 256);                // 1 thread/sample
    dqn_sim<<<g2, blk, 0, stream>>>(half_ang, q_par, post_w, post_b, out, nsamp);
}